// Round 4
// baseline (407.199 us; speedup 1.0000x reference)
//
#include <hip/hip_runtime.h>

// SRLoss: loss = mean((inp - avgpool10x10(output))^2) + BCE(output, target)
// output/target: [32,1,1280,1280] f32; inp: [32,1,128,128] f32; out: scalar f32.
//
// R7 post-mortem: removing the final atomic changed NOTHING (136us, same
// counters) -> atomic theory refuted. The real tell: VGPR_Count=44, but the
// PD=5 rotating pipeline needs >=40 VGPRs of float4 buffers alone. The
// compiler collapsed the pipeline (sank loads next to uses) -> ~2 loads in
// flight per wave -> per-block lifetime ~ 20 serialized latencies ~ 8.5us.
// Pure MLP deficit, not bandwidth (HBM at 19%).
// R8: flat FULL PRELOAD of all 20 float4s, interleaved o,t,o,t (first use
// waits vmcnt(18)), then compute. ~100 VGPR, under the (320,4) cap of 128.
// Signature to check: VGPR_Count ~95-110. If still ~44, compiler sank loads
// again -> inline-asm next. Two-kernel reduction kept (proven free, det.).

#define BATCH 32
#define HH 1280
#define WW 1280
#define PH 128
#define PW 128
#define SC 10
#define NT 320                      // threads per block (5 waves)
#define KD 10                      // float4-pair iterations per thread
#define NB (BATCH * PH)            // 4096 blocks
#define NT2 512                    // reduce-kernel threads

static constexpr float EPSV = 1e-20f;
static constexpr float LN2  = 0.6931471805599453f;
static constexpr float INV_NBCE = 1.0f / (float)(BATCH * HH * WW);   // bce mean
static constexpr float INV_NM   = 1.0f / (float)(BATCH * PH * PW);   // mse mean

__global__ __launch_bounds__(NT, 4) void srloss_partial(
    const float* __restrict__ output,
    const float* __restrict__ target,
    const float* __restrict__ inp,
    float* __restrict__ partials)
{
    __shared__ float psum[PW];      // pooled column sums for this band
    __shared__ float red[NT / 64];  // cross-wave reduction scratch

    const int t = threadIdx.x;
    const int band = blockIdx.x;    // 0 .. BATCH*PH-1
    const int b = band >> 7;        // band / 128
    const int pr = band & 127;      // band % 128

    if (t < PW) psum[t] = 0.0f;
    __syncthreads();                // before any loads issue (no vmcnt drain)

    const size_t base = ((size_t)b * HH + (size_t)pr * SC) * WW;
    const float4* __restrict__ o4p = (const float4*)(output + base) + t;
    const float4* __restrict__ t4p = (const float4*)(target + base) + t;

    // FULL PRELOAD: all 20 16B loads issued back-to-back, interleaved o,t so
    // the first consumer needs only the two oldest (vmcnt(18)). All indices
    // compile-time -> registers, no scratch (rule: static indexing only).
    float4 ob[KD], tb[KD];
    #pragma unroll
    for (int k = 0; k < KD; ++k) {
        ob[k] = o4p[NT * k];
        tb[k] = t4p[NT * k];
    }

    float acc2 = 0.0f;              // sum log2(oc)
    float accd = 0.0f;              // sum t*(log2(om)-log2(oc))
    float s0 = 0.0f, s1 = 0.0f;     // pooled sums: halves of the float4
    #pragma unroll
    for (int k = 0; k < KD; ++k) {
        const float o[4]  = {ob[k].x, ob[k].y, ob[k].z, ob[k].w};
        const float tg[4] = {tb[k].x, tb[k].y, tb[k].z, tb[k].w};
        #pragma unroll
        for (int j = 0; j < 4; ++j) {
            const float om = fmaxf(o[j], EPSV);
            const float oc = fmaxf(1.0f - o[j], EPSV);
            const float l1 = __log2f(om);
            const float l2 = __log2f(oc);
            acc2 += l2;
            accd += tg[j] * (l1 - l2);
        }
        s0 += o[0] + o[1];
        s1 += o[2] + o[3];
    }
    const float bce_acc = LN2 * (acc2 + accd);

    // c = t + 320k -> row = k, col0 = 4t for all k (k-invariant mapping)
    const int col0 = 4 * t;
    const int p0 = col0 / SC;
    if ((col0 % SC) == 8) {         // straddle: o[2],o[3] belong to p0+1
        atomicAdd(&psum[p0],     s0);
        atomicAdd(&psum[p0 + 1], s1);
    } else {
        atomicAdd(&psum[p0], s0 + s1);
    }
    __syncthreads();

    // MSE terms: one pooled element per thread for t < 128
    float mse_acc = 0.0f;
    if (t < PW) {
        const float pooled = psum[t] * (1.0f / (float)(SC * SC));
        const float iv = inp[(size_t)band * PW + t];
        const float d = iv - pooled;
        mse_acc = d * d;
    }

    // per-block contribution, pre-normalized
    float contrib = (-INV_NBCE) * bce_acc + INV_NM * mse_acc;

    #pragma unroll
    for (int off = 32; off > 0; off >>= 1)
        contrib += __shfl_down(contrib, off, 64);
    if ((t & 63) == 0) red[t >> 6] = contrib;
    __syncthreads();

    // plain store to a distinct slot: no RMW chain, no fence
    if (t == 0) {
        float s = 0.0f;
        #pragma unroll
        for (int w = 0; w < NT / 64; ++w) s += red[w];
        partials[band] = s;
    }
}

__global__ __launch_bounds__(NT2) void srloss_reduce(
    const float* __restrict__ partials,
    float* __restrict__ out)
{
    __shared__ float red[NT2 / 64];
    const int t = threadIdx.x;

    // 4096 floats = 1024 float4; 512 threads x 2 float4 each
    const float4 v0 = ((const float4*)partials)[t];
    const float4 v1 = ((const float4*)partials)[t + NT2];
    float s = (v0.x + v0.y) + (v0.z + v0.w) + (v1.x + v1.y) + (v1.z + v1.w);

    #pragma unroll
    for (int off = 32; off > 0; off >>= 1)
        s += __shfl_down(s, off, 64);
    if ((t & 63) == 0) red[t >> 6] = s;
    __syncthreads();
    if (t == 0) {
        float tot = 0.0f;
        #pragma unroll
        for (int w = 0; w < NT2 / 64; ++w) tot += red[w];
        out[0] = tot;
    }
}

extern "C" void kernel_launch(void* const* d_in, const int* in_sizes, int n_in,
                              void* d_out, int out_size, void* d_ws, size_t ws_size,
                              hipStream_t stream) {
    const float* output = (const float*)d_in[0];
    const float* target = (const float*)d_in[1];
    const float* inp    = (const float*)d_in[2];
    float* out = (float*)d_out;
    float* partials = (float*)d_ws;              // 4096 floats = 16 KB

    srloss_partial<<<NB, NT, 0, stream>>>(output, target, inp, partials);
    srloss_reduce<<<1, NT2, 0, stream>>>(partials, out);
}

// Round 5
// 406.664 us; speedup vs baseline: 1.0013x; 1.0013x over previous
//
#include <hip/hip_runtime.h>

// SRLoss: loss = mean((inp - avgpool10x10(output))^2) + BCE(output, target)
// output/target: [32,1,1280,1280] f32; inp: [32,1,128,128] f32; out: scalar f32.
//
// R8 post-mortem: source-level full preload was DEFEATED — VGPR_Count stayed
// 44 (20 float4 buffers need 80), dur unchanged 137us. hipcc sinks loads next
// to uses to minimize pressure; the compiled load path has been identical
// since R4. MLP theory (only ~2 loads in flight/wave -> latency-serialized)
// is still live and untested.
// R9: FORCE it. All 20 global_load_dwordx4 issued as asm volatile (cannot be
// sunk/reordered), then s_waitcnt vmcnt(0) + sched_barrier(0) (rule #18:
// without sched_barrier hipcc hoists register-only consumers above the
// waitcnt asm), then unchanged compute. Signature: VGPR ~100-128. If VGPR
// jumps but dur stays 137us -> per-wave MLP is NOT the limiter; go after
// CU-level residency next. Two-kernel deterministic reduce kept.

#define BATCH 32
#define HH 1280
#define WW 1280
#define PH 128
#define PW 128
#define SC 10
#define NT 320                      // threads per block (5 waves)
#define KD 10                      // float4-pair iterations per thread
#define NB (BATCH * PH)            // 4096 blocks
#define NT2 512                    // reduce-kernel threads

static constexpr float EPSV = 1e-20f;
static constexpr float LN2  = 0.6931471805599453f;
static constexpr float INV_NBCE = 1.0f / (float)(BATCH * HH * WW);   // bce mean
static constexpr float INV_NM   = 1.0f / (float)(BATCH * PH * PW);   // mse mean

__global__ __launch_bounds__(NT, 4) void srloss_partial(
    const float* __restrict__ output,
    const float* __restrict__ target,
    const float* __restrict__ inp,
    float* __restrict__ partials)
{
    __shared__ float psum[PW];      // pooled column sums for this band
    __shared__ float red[NT / 64];  // cross-wave reduction scratch

    const int t = threadIdx.x;
    const int band = blockIdx.x;    // 0 .. BATCH*PH-1
    const int b = band >> 7;        // band / 128
    const int pr = band & 127;      // band % 128

    if (t < PW) psum[t] = 0.0f;
    __syncthreads();                // before any loads issue (no vmcnt drain)

    const size_t base = ((size_t)b * HH + (size_t)pr * SC) * WW;
    const float4* __restrict__ o4p = (const float4*)(output + base) + t;
    const float4* __restrict__ t4p = (const float4*)(target + base) + t;

    // FORCED full preload: 20 x global_load_dwordx4 as volatile asm — the
    // compiler cannot sink these. 80 VGPRs of destinations stay live; 20 KB
    // in flight per wave at issue time.
    float4 ob[KD], tb[KD];
    #pragma unroll
    for (int k = 0; k < KD; ++k) {
        asm volatile("global_load_dwordx4 %0, %1, off"
                     : "=v"(ob[k]) : "v"(o4p + NT * k));
        asm volatile("global_load_dwordx4 %0, %1, off"
                     : "=v"(tb[k]) : "v"(t4p + NT * k));
    }
    asm volatile("s_waitcnt vmcnt(0)" ::: "memory");
    __builtin_amdgcn_sched_barrier(0);   // rule #18: pin consumers below wait

    float acc2 = 0.0f;              // sum log2(oc)
    float accd = 0.0f;              // sum t*(log2(om)-log2(oc))
    float s0 = 0.0f, s1 = 0.0f;     // pooled sums: halves of the float4
    #pragma unroll
    for (int k = 0; k < KD; ++k) {
        const float o[4]  = {ob[k].x, ob[k].y, ob[k].z, ob[k].w};
        const float tg[4] = {tb[k].x, tb[k].y, tb[k].z, tb[k].w};
        #pragma unroll
        for (int j = 0; j < 4; ++j) {
            const float om = fmaxf(o[j], EPSV);
            const float oc = fmaxf(1.0f - o[j], EPSV);
            const float l1 = __log2f(om);
            const float l2 = __log2f(oc);
            acc2 += l2;
            accd += tg[j] * (l1 - l2);
        }
        s0 += o[0] + o[1];
        s1 += o[2] + o[3];
    }
    const float bce_acc = LN2 * (acc2 + accd);

    // c = t + 320k -> row = k, col0 = 4t for all k (k-invariant mapping)
    const int col0 = 4 * t;
    const int p0 = col0 / SC;
    if ((col0 % SC) == 8) {         // straddle: o[2],o[3] belong to p0+1
        atomicAdd(&psum[p0],     s0);
        atomicAdd(&psum[p0 + 1], s1);
    } else {
        atomicAdd(&psum[p0], s0 + s1);
    }
    __syncthreads();

    // MSE terms: one pooled element per thread for t < 128
    float mse_acc = 0.0f;
    if (t < PW) {
        const float pooled = psum[t] * (1.0f / (float)(SC * SC));
        const float iv = inp[(size_t)band * PW + t];
        const float d = iv - pooled;
        mse_acc = d * d;
    }

    // per-block contribution, pre-normalized
    float contrib = (-INV_NBCE) * bce_acc + INV_NM * mse_acc;

    #pragma unroll
    for (int off = 32; off > 0; off >>= 1)
        contrib += __shfl_down(contrib, off, 64);
    if ((t & 63) == 0) red[t >> 6] = contrib;
    __syncthreads();

    // plain store to a distinct slot: no RMW chain, no fence
    if (t == 0) {
        float s = 0.0f;
        #pragma unroll
        for (int w = 0; w < NT / 64; ++w) s += red[w];
        partials[band] = s;
    }
}

__global__ __launch_bounds__(NT2) void srloss_reduce(
    const float* __restrict__ partials,
    float* __restrict__ out)
{
    __shared__ float red[NT2 / 64];
    const int t = threadIdx.x;

    // 4096 floats = 1024 float4; 512 threads x 2 float4 each
    const float4 v0 = ((const float4*)partials)[t];
    const float4 v1 = ((const float4*)partials)[t + NT2];
    float s = (v0.x + v0.y) + (v0.z + v0.w) + (v1.x + v1.y) + (v1.z + v1.w);

    #pragma unroll
    for (int off = 32; off > 0; off >>= 1)
        s += __shfl_down(s, off, 64);
    if ((t & 63) == 0) red[t >> 6] = s;
    __syncthreads();
    if (t == 0) {
        float tot = 0.0f;
        #pragma unroll
        for (int w = 0; w < NT2 / 64; ++w) tot += red[w];
        out[0] = tot;
    }
}

extern "C" void kernel_launch(void* const* d_in, const int* in_sizes, int n_in,
                              void* d_out, int out_size, void* d_ws, size_t ws_size,
                              hipStream_t stream) {
    const float* output = (const float*)d_in[0];
    const float* target = (const float*)d_in[1];
    const float* inp    = (const float*)d_in[2];
    float* out = (float*)d_out;
    float* partials = (float*)d_ws;              // 4096 floats = 16 KB

    srloss_partial<<<NB, NT, 0, stream>>>(output, target, inp, partials);
    srloss_reduce<<<1, NT2, 0, stream>>>(partials, out);
}